// Round 17
// baseline (593.975 us; speedup 1.0000x reference)
//
#include <hip/hip_runtime.h>
#include <math.h>

#define PI_F 3.14159265358979323846f

// ---------------------------------------------------------------------------
// N_ORDER=256, PRED_LEN=192, SEQ_LEN=768, ENC_IN=21, B=16, L_s=192<<s, MODES=32
//
// Pipeline (all linear in x; kernel-matrix construction then one apply):
//   w_d = A^d B                      (doubling chain; transpose+Y co-scheduled
//                                     in the chain launches' latency shadow)
//   Wt[(s,ri,k)][i][o] = W[i][o][k]  (transpose, LDS-staged; rides launch 0)
//   Y[z][p][i] = sum_o Wt[z][i][o] E[L-192+p][o]  (GEMM; rides launches 1..8)
//   Qb[s][d][n] = sum_i w_d[i] Y[n][i],  n=(ri,k,p)        (GEMM, 8.5 GF)
//   Z[k][d][p] = sum_{d'<=d} e^{-2pi i k d'/L} Q[k][d'][p] (chunked scan)
//   F[s][sidx][k][p] = c_k Re(e^{2pi i k((191-sidx)%L)/L} Z[k][L-1-sidx][p])
//   Ktot[tau][p] = sum_s mlp_w[s] * sum_k F[s][tau-(768-L_s)][k][p]  (fused)
//   out[b][p][c] = sum_tau x[b][tau][c] Ktot[tau][p] + mlp_b
//
// Workspace layout (float offsets):
//   w    [s][d][i]        : 0        len 344064
//   Apow [s][2][65536]    : 344064   len 393216
//   Ktil (unused)         : 737280   len 258048
//   Ktot [tau][p]         : 995328   len 147456
//   Y    [z][p][i]        : 1142784  len 9437184   (dead after k_gemm_Q4;
//        S (chunk sums)   : 1142784  len 589824     reused by scan)
//        F (folded)       : 1732608  len 8257536
//   QT region (time-shared):
//     Wt [z][i][o]        : 10579968 len 12582912
//     Qb [s][d][12288]    : 10579968 len 16515072
// Total 27,095,040 floats (proven to fit)
// ---------------------------------------------------------------------------
#define W_OFF    0
#define AP_OFF   344064
#define KT_OFF   737280
#define KTOT_OFF 995328
#define Y_OFF    1142784
#define S_OFF    1142784
#define F_OFF    1732608
#define QT_OFF   10579968
#define WS_FLOATS 27095040

__device__ __forceinline__ int off_w_f(int s)  { return 49152  * ((1 << s) - 1); }
__device__ __forceinline__ int qoff_f(int s)   { return 2359296 * ((1 << s) - 1); }
__device__ __forceinline__ int foff_f(int s)   { return 1179648 * ((1 << s) - 1); }

// ---------------------------------------------------------------------------
// Chain tile: C[32x64 tile at (m0,n0)] = A[M x 256] @ op(B[256 x 256]),
// 256 threads, 2x4 microtile.  fmaf chain over k ascending in 16-chunks.
// ---------------------------------------------------------------------------
template<bool BT>
__device__ __forceinline__ void gemm_tile32(const float* __restrict__ A,
                                            const float* __restrict__ B,
                                            float* __restrict__ C,
                                            int M, int ldc, int m0, int n0)
{
    __shared__ float As[16][36];
    __shared__ float Bs[16][68];
    const int tid = threadIdx.x;
    const int tx = tid & 15;
    const int ty = tid >> 4;

    float acc[2][4] = {{0.f,0.f,0.f,0.f},{0.f,0.f,0.f,0.f}};

    for (int kk = 0; kk < 256; kk += 16) {
        if (tid < 128) {
            int r  = tid >> 2;
            int kq = (tid & 3) << 2;
            float4 av = make_float4(0.f, 0.f, 0.f, 0.f);
            if (m0 + r < M)
                av = *(const float4*)(A + (size_t)(m0 + r) * 256 + kk + kq);
            As[kq + 0][r] = av.x; As[kq + 1][r] = av.y;
            As[kq + 2][r] = av.z; As[kq + 3][r] = av.w;
        }
        if (BT) {
            int rb = tid >> 2;
            int kq = (tid & 3) << 2;
            float4 bv = *(const float4*)(B + (size_t)(n0 + rb) * 256 + kk + kq);
            Bs[kq + 0][rb] = bv.x; Bs[kq + 1][rb] = bv.y;
            Bs[kq + 2][rb] = bv.z; Bs[kq + 3][rb] = bv.w;
        } else {
            int kb = tid >> 4;
            int j4 = (tid & 15) << 2;
            float4 bv = *(const float4*)(B + (size_t)(kk + kb) * 256 + n0 + j4);
            *(float4*)(&Bs[kb][j4]) = bv;
        }
        __syncthreads();

        #pragma unroll
        for (int kq = 0; kq < 16; ++kq) {
            float a0 = As[kq][2 * ty];
            float a1 = As[kq][2 * ty + 1];
            float4 b4 = *(const float4*)(&Bs[kq][tx << 2]);
            acc[0][0] = fmaf(a0, b4.x, acc[0][0]);
            acc[0][1] = fmaf(a0, b4.y, acc[0][1]);
            acc[0][2] = fmaf(a0, b4.z, acc[0][2]);
            acc[0][3] = fmaf(a0, b4.w, acc[0][3]);
            acc[1][0] = fmaf(a1, b4.x, acc[1][0]);
            acc[1][1] = fmaf(a1, b4.y, acc[1][1]);
            acc[1][2] = fmaf(a1, b4.z, acc[1][2]);
            acc[1][3] = fmaf(a1, b4.w, acc[1][3]);
        }
        __syncthreads();
    }

    #pragma unroll
    for (int u = 0; u < 2; ++u) {
        int row = m0 + 2 * ty + u;
        if (row < M) {
            float4 cv = make_float4(acc[u][0], acc[u][1], acc[u][2], acc[u][3]);
            *(float4*)(C + (size_t)row * ldc + n0 + (tx << 2)) = cv;
        }
    }
}

// ---------------------------------------------------------------------------
// Workhorse (r7-proven): C[64][128] = A[64][256] @ B^T, K=256, 256 threads,
// 4x8 microtile, single-buffered.
// ---------------------------------------------------------------------------
__device__ __forceinline__ void gemm64x128_q(const float* __restrict__ A,
                                             const float* __restrict__ B,
                                             float* __restrict__ C, int ldc)
{
    __shared__ float As[16][68];
    __shared__ float Bs[16][132];

    const int tid = threadIdx.x;
    const int tx = tid & 15;
    const int ty = tid >> 4;
    const int ra  = tid >> 2;          // 0..63
    const int kqa = (tid & 3) << 2;    // 0,4,8,12
    const int rb  = tid >> 1;          // 0..127
    const int kq8 = (tid & 1) << 3;    // 0 or 8

    float acc[2][4][4];
    #pragma unroll
    for (int g = 0; g < 2; ++g)
        #pragma unroll
        for (int u = 0; u < 4; ++u)
            #pragma unroll
            for (int v = 0; v < 4; ++v) acc[g][u][v] = 0.f;

    for (int kk = 0; kk < 256; kk += 16) {
        float4 av = *(const float4*)(A + (size_t)ra * 256 + kk + kqa);
        As[kqa + 0][ra] = av.x; As[kqa + 1][ra] = av.y;
        As[kqa + 2][ra] = av.z; As[kqa + 3][ra] = av.w;

        const float* bp = B + (size_t)rb * 256 + kk + kq8;
        float4 b0 = *(const float4*)(bp);
        float4 b1 = *(const float4*)(bp + 4);
        Bs[kq8 + 0][rb] = b0.x; Bs[kq8 + 1][rb] = b0.y;
        Bs[kq8 + 2][rb] = b0.z; Bs[kq8 + 3][rb] = b0.w;
        Bs[kq8 + 4][rb] = b1.x; Bs[kq8 + 5][rb] = b1.y;
        Bs[kq8 + 6][rb] = b1.z; Bs[kq8 + 7][rb] = b1.w;
        __syncthreads();

        #pragma unroll
        for (int kq = 0; kq < 16; ++kq) {
            float4 a   = *(const float4*)(&As[kq][4 * ty]);
            float4 b0v = *(const float4*)(&Bs[kq][4 * tx]);
            float4 b1v = *(const float4*)(&Bs[kq][4 * tx + 64]);
            float af[4] = {a.x, a.y, a.z, a.w};
            float bf[8] = {b0v.x, b0v.y, b0v.z, b0v.w, b1v.x, b1v.y, b1v.z, b1v.w};
            #pragma unroll
            for (int g = 0; g < 2; ++g)
                #pragma unroll
                for (int u = 0; u < 4; ++u)
                    #pragma unroll
                    for (int v = 0; v < 4; ++v)
                        acc[g][u][v] = fmaf(af[u], bf[g * 4 + v], acc[g][u][v]);
        }
        __syncthreads();
    }

    #pragma unroll
    for (int u = 0; u < 4; ++u) {
        int row = 4 * ty + u;
        #pragma unroll
        for (int g = 0; g < 2; ++g) {
            float4 cv = make_float4(acc[g][u][0], acc[g][u][1],
                                    acc[g][u][2], acc[g][u][3]);
            *(float4*)(C + (size_t)row * ldc + 4 * tx + 64 * g) = cv;
        }
    }
}

// ---------------------------------------------------------------------------
// Transpose body: Wt[s][ri][k][i][o] = W[i][o][k]  (LDS-staged, coalesced)
// ---------------------------------------------------------------------------
__device__ __forceinline__ void transpose_body(int bid,
    const float* Wr0, const float* Wi0, const float* Wr1, const float* Wi1,
    const float* Wr2, const float* Wi2, float* ws)
{
    __shared__ float t[256][33];
    int i  = bid & 255;
    int ri = (bid >> 8) & 1;
    int s  = bid >> 9;
    const float* W;
    if (s == 0)      W = ri ? Wi0 : Wr0;
    else if (s == 1) W = ri ? Wi1 : Wr1;
    else             W = ri ? Wi2 : Wr2;

    const int tid = threadIdx.x;
    const float* slab = W + (size_t)i * 8192;
    #pragma unroll
    for (int j = 0; j < 8; ++j) {
        int f = j * 1024 + tid * 4;
        float4 v = *(const float4*)(slab + f);
        int o = f >> 5;
        int k = f & 31;
        t[o][k + 0] = v.x; t[o][k + 1] = v.y;
        t[o][k + 2] = v.z; t[o][k + 3] = v.w;
    }
    __syncthreads();

    int sri = s * 2 + ri;
    #pragma unroll
    for (int k = 0; k < 32; ++k) {
        ws[QT_OFF + (size_t)(sri * 32 + k) * 65536 + (size_t)i * 256 + tid] = t[tid][k];
    }
}

// ---------------------------------------------------------------------------
// Y body: Y[z][p][i] = sum_o E[L-192+p][o] * Wt[z][i][o]   (q-tile)
// ---------------------------------------------------------------------------
__device__ __forceinline__ void y_body(int yz, int n0, int m0,
    const float* E0, const float* E1, const float* E2, float* ws)
{
    const int s = yz >> 6;
    const int L = 192 << s;
    const float* E = (s == 0) ? E0 : (s == 1) ? E1 : E2;
    const float* Ap = E + (size_t)(L - 192) * 256 + (size_t)m0 * 256;
    const float* Bp = ws + QT_OFF + (size_t)yz * 65536 + (size_t)n0 * 256;
    float* Cp = ws + Y_OFF + (size_t)yz * 49152 + (size_t)m0 * 256 + n0;
    gemm64x128_q(Ap, Bp, Cp, 256);
}

// ---------------------------------------------------------------------------
// Merged chain launch:
//   z < nz_lev          : doubling level n for scale s = z + sbase
//   z >= nz_lev, n == 0 : transpose block bid = (z-nz_lev)*64 + y*4 + x
//   z >= nz_lev, n >= 1 : Y block yz = ylo + (z-nz_lev), active if x<2 && y<3
// ---------------------------------------------------------------------------
__global__ void __launch_bounds__(256)
k_level3(int n, int sbase, int nz_lev, int ylo,
         const float* A0, const float* A1, const float* A2,
         const float* B0, const float* B1, const float* B2,
         const float* E0, const float* E1, const float* E2,
         const float* Wr0, const float* Wi0, const float* Wr1, const float* Wi1,
         const float* Wr2, const float* Wi2, float* ws)
{
    const int z = blockIdx.z;
    if (z < nz_lev) {
        int s = z + sbase;
        int L = 192 << s;
        const float* Ain = (s == 0) ? A0 : (s == 1) ? A1 : A2;
        const float* Bv  = (s == 0) ? B0 : (s == 1) ? B1 : B2;
        float* wbase = ws + W_OFF + off_w_f(s);
        float* bufA  = ws + AP_OFF + s * 131072;
        float* bufB  = bufA + 65536;
        const float* src = (n == 0) ? Ain : (((n - 1) & 1) ? bufB : bufA);

        const int y = blockIdx.y;
        const int n0col = blockIdx.x * 64;

        if (n == 0 && y == 15 && blockIdx.x == 3)
            ws[W_OFF + off_w_f(s) + threadIdx.x] = Bv[threadIdx.x];

        if (y < 8) {
            int p2 = 1 << n;
            if (p2 >= L) return;
            int cnt = min(p2, L - p2);
            int m0 = y * 32;
            if (m0 >= cnt) return;
            const float* Aop = (n == 0) ? Bv : wbase;   // n=0: w[0] == Bv
            gemm_tile32<true>(Aop, src, wbase + (size_t)p2 * 256, cnt, 256, m0, n0col);
        } else {
            if ((2 << n) >= L) return;
            float* dst = (n & 1) ? bufB : bufA;
            gemm_tile32<false>(src, src, dst, 256, 256, (y - 8) * 32, n0col);
        }
        return;
    }

    if (n == 0) {
        int bid = (z - nz_lev) * 64 + blockIdx.y * 4 + blockIdx.x;
        transpose_body(bid, Wr0, Wi0, Wr1, Wi1, Wr2, Wi2, ws);
        return;
    }

    if (blockIdx.x >= 2 || blockIdx.y >= 3) return;
    int yz = ylo + (z - nz_lev);
    y_body(yz, blockIdx.x * 128, blockIdx.y * 64, E0, E1, E2, ws);
}

// ---------------------------------------------------------------------------
// Qb[s][d][n] = sum_i w[s][d][i] * Y[n][i],  n = (ri*32+k)*192+p
// grid (96, 21): x = 128-col tile of n, y = packed (s, d-tile).  256 threads.
// ---------------------------------------------------------------------------
__global__ void __launch_bounds__(256, 4)
k_gemm_Q4(float* __restrict__ ws)
{
    const int y = blockIdx.y;
    int s, yt;
    if (y < 3)      { s = 0; yt = y; }
    else if (y < 9) { s = 1; yt = y - 3; }
    else            { s = 2; yt = y - 9; }
    const int m0 = yt * 64;
    const int n0 = blockIdx.x * 128;

    const float* Ap = ws + W_OFF + off_w_f(s) + (size_t)m0 * 256;
    const float* Bp = ws + Y_OFF + (size_t)s * 3145728 + (size_t)n0 * 256;
    float* Cp = ws + QT_OFF + qoff_f(s) + (size_t)m0 * 12288 + n0;
    gemm64x128_q(Ap, Bp, Cp, 12288);
}

// ---------------------------------------------------------------------------
// Pass 1 of chunked twiddled scan: complex chunk sums (16 chunks of L/16).
// grid (16, 32, 3), block 192 (= p)
// ---------------------------------------------------------------------------
__global__ void k_scanA(float* __restrict__ ws)
{
    const int c = blockIdx.x;
    const int k = blockIdx.y;
    const int s = blockIdx.z;
    const int L = 192 << s;
    const int C = L >> 4;
    const int p = threadIdx.x;

    __shared__ float twc[768], tws[768];
    for (int m = p; m < L; m += 192) {
        float ang = -2.f * PI_F * (float)m / (float)L;
        float ss, cc; sincosf(ang, &ss, &cc);
        twc[m] = cc; tws[m] = ss;
    }
    __syncthreads();

    const float* Qr = ws + QT_OFF + qoff_f(s) + (size_t)k * 192;
    const float* Qi = Qr + 6144;

    float ar = 0.f, ai = 0.f;
    const int d0 = c * C;
    int ph = (k * d0) % L;
    for (int j = 0; j < C; ++j) {
        int d = d0 + j;
        float qr = Qr[(size_t)d * 12288 + p];
        float qi = Qi[(size_t)d * 12288 + p];
        float cc = twc[ph], sn = tws[ph];
        ar = fmaf(cc, qr, fmaf(-sn, qi, ar));
        ai = fmaf(cc, qi, fmaf( sn, qr, ai));
        ph += k; if (ph >= L) ph -= L;
    }
    size_t sb = (size_t)((s * 32 + k) * 16 + c) * 384;
    ws[S_OFF + sb + p]       = ar;
    ws[S_OFF + sb + 192 + p] = ai;
}

// ---------------------------------------------------------------------------
// Pass 2: offset from chunk sums, rescan own chunk, fold phase into F.
// grid (16, 32, 3), block 192
// ---------------------------------------------------------------------------
__global__ void k_scanB(float* __restrict__ ws)
{
    const int c = blockIdx.x;
    const int k = blockIdx.y;
    const int s = blockIdx.z;
    const int L = 192 << s;
    const int C = L >> 4;
    const int p = threadIdx.x;

    __shared__ float twc[768], tws[768];
    for (int m = p; m < L; m += 192) {
        float ang = -2.f * PI_F * (float)m / (float)L;
        float ss, cc; sincosf(ang, &ss, &cc);
        twc[m] = cc; tws[m] = ss;
    }
    __syncthreads();

    float ar = 0.f, ai = 0.f;
    size_t sbase = (size_t)(s * 32 + k) * 16 * 384;
    for (int c2 = 0; c2 < c; ++c2) {
        ar += ws[S_OFF + sbase + (size_t)c2 * 384 + p];
        ai += ws[S_OFF + sbase + (size_t)c2 * 384 + 192 + p];
    }

    const float ck = ((k == 0) ? 1.f : 2.f) / (float)L;
    const float* Qr = ws + QT_OFF + qoff_f(s) + (size_t)k * 192;
    const float* Qi = Qr + 6144;
    float* F = ws + F_OFF + foff_f(s);

    const int d0 = c * C;
    int ph = (k * d0) % L;
    int m1 = d0 + 192 - L; if (m1 < 0) m1 += L;
    int ph2 = (k * m1) % L;
    for (int j = 0; j < C; ++j) {
        int d = d0 + j;
        float qr = Qr[(size_t)d * 12288 + p];
        float qi = Qi[(size_t)d * 12288 + p];
        float cc = twc[ph], sn = tws[ph];
        ar = fmaf(cc, qr, fmaf(-sn, qi, ar));
        ai = fmaf(cc, qi, fmaf( sn, qr, ai));
        float f = ck * fmaf(twc[ph2], ar, tws[ph2] * ai);
        int sidx = L - 1 - d;
        F[((size_t)sidx * 32 + k) * 192 + p] = f;
        ph  += k; if (ph  >= L) ph  -= L;
        ph2 += k; if (ph2 >= L) ph2 -= L;
    }
}

// ---------------------------------------------------------------------------
// Fused k-reduction + scale-combine:
//   Ktot[tau][p] = sum_s (tau >= 768-L_s) mlp_w[s] * sum_k F[s][tau-(768-L_s)][k][p]
// grid (768), block 192
// ---------------------------------------------------------------------------
__global__ void k_kredc(float* __restrict__ ws, const float* __restrict__ mw)
{
    const int tau = blockIdx.x;
    const int p   = threadIdx.x;
    float sum = 0.f;
    #pragma unroll
    for (int s = 0; s < 3; ++s) {
        int L = 192 << s;
        int off = 768 - L;
        if (tau >= off) {
            int sidx = tau - off;
            const float* F = ws + F_OFF + foff_f(s) + (size_t)sidx * 32 * 192;
            float kt = 0.f;
            #pragma unroll
            for (int k = 0; k < 32; ++k)
                kt += F[k * 192 + p];
            sum = fmaf(mw[s], kt, sum);
        }
    }
    ws[KTOT_OFF + (size_t)tau * 192 + p] = sum;
}

// ---------------------------------------------------------------------------
__global__ void k_out(const float* __restrict__ x, const float* __restrict__ ws,
                      const float* __restrict__ mb, float* __restrict__ out)
{
    int bid = blockIdx.x;
    int b = bid / 21;
    int c = bid - b * 21;
    __shared__ float xl[768];
    for (int t = threadIdx.x; t < 768; t += 192)
        xl[t] = x[((size_t)b * 768 + t) * 21 + c];
    __syncthreads();

    int p = threadIdx.x;
    const float* K = ws + KTOT_OFF;
    float acc = 0.f;
    for (int tau = 0; tau < 768; ++tau)
        acc = fmaf(xl[tau], K[(size_t)tau * 192 + p], acc);
    out[((size_t)b * 192 + p) * 21 + c] = acc + mb[0];
}

// ---------------------------------------------------------------------------
extern "C" void kernel_launch(void* const* d_in, const int* in_sizes, int n_in,
                              void* d_out, int out_size, void* d_ws, size_t ws_size,
                              hipStream_t stream)
{
    const float* x   = (const float*)d_in[0];
    const float* A0  = (const float*)d_in[1];
    const float* B0  = (const float*)d_in[2];
    const float* E0  = (const float*)d_in[3];
    const float* Wr0 = (const float*)d_in[4];
    const float* Wi0 = (const float*)d_in[5];
    const float* A1  = (const float*)d_in[6];
    const float* B1  = (const float*)d_in[7];
    const float* E1  = (const float*)d_in[8];
    const float* Wr1 = (const float*)d_in[9];
    const float* Wi1 = (const float*)d_in[10];
    const float* A2  = (const float*)d_in[11];
    const float* B2  = (const float*)d_in[12];
    const float* E2  = (const float*)d_in[13];
    const float* Wr2 = (const float*)d_in[14];
    const float* Wi2 = (const float*)d_in[15];
    const float* mw  = (const float*)d_in[16];
    const float* mb  = (const float*)d_in[17];
    float* ws  = (float*)d_ws;
    float* out = (float*)d_out;

    if (ws_size < (size_t)WS_FLOATS * sizeof(float)) {
        hipMemsetAsync(d_out, 0, (size_t)out_size * sizeof(float), stream);
        return;
    }

    // n=0: levels (3 scales) + all 1536 transpose blocks (24 z-slots)
    k_level3<<<dim3(4, 16, 27), 256, 0, stream>>>(0, 0, 3, 0,
        A0, A1, A2, B0, B1, B2, E0, E1, E2, Wr0, Wi0, Wr1, Wi1, Wr2, Wi2, ws);
    // n=1..7: levels (3 scales) + Y z-slice [24(n-1), 24n)
    for (int n = 1; n < 8; ++n)
        k_level3<<<dim3(4, 16, 27), 256, 0, stream>>>(n, 0, 3, 24 * (n - 1),
            A0, A1, A2, B0, B1, B2, E0, E1, E2, Wr0, Wi0, Wr1, Wi1, Wr2, Wi2, ws);
    // n=8: levels s=1 (jump 128 rows), s=2 + Y z-slice [168, 192)
    k_level3<<<dim3(4, 16, 26), 256, 0, stream>>>(8, 1, 2, 168,
        A0, A1, A2, B0, B1, B2, E0, E1, E2, Wr0, Wi0, Wr1, Wi1, Wr2, Wi2, ws);
    // n=9: level s=2 only
    k_level3<<<dim3(4, 16, 1), 256, 0, stream>>>(9, 2, 1, 0,
        A0, A1, A2, B0, B1, B2, E0, E1, E2, Wr0, Wi0, Wr1, Wi1, Wr2, Wi2, ws);

    k_gemm_Q4<<<dim3(96, 21), 256, 0, stream>>>(ws);
    k_scanA<<<dim3(16, 32, 3), 192, 0, stream>>>(ws);
    k_scanB<<<dim3(16, 32, 3), 192, 0, stream>>>(ws);
    k_kredc<<<768, 192, 0, stream>>>(ws, mw);
    k_out<<<336, 192, 0, stream>>>(x, ws, mb, out);
}

// Round 18
// 395.928 us; speedup vs baseline: 1.5002x; 1.5002x over previous
//
#include <hip/hip_runtime.h>
#include <math.h>

#define PI_F 3.14159265358979323846f

// ---------------------------------------------------------------------------
// N_ORDER=256, PRED_LEN=192, SEQ_LEN=768, ENC_IN=21, B=16, L_s=192<<s, MODES=32
//
// Pipeline (all linear in x; kernel-matrix construction then one apply):
//   w_d = A^d B                      (doubling chain; transpose rides level-0)
//   Wt[(s,ri,k)][i][o] = W[i][o][k]  (transpose, LDS-staged)
//   Y[z][p][i] = sum_o Wt[z][i][o] E[L-192+p][o]           (GEMM, 4.8 GF)
//   Qb[s][d][n] = sum_i w_d[i] Y[n][i],  n=(ri,k,p)        (GEMM, 8.5 GF)
//   Z[k][d][p] = sum_{d'<=d} e^{-2pi i k d'/L} Q[k][d'][p] (chunked scan)
//   F[s][sidx][k][p] = c_k Re(e^{2pi i k((191-sidx)%L)/L} Z[k][L-1-sidx][p])
//   Ktot[tau][p] = sum_s mlp_w[s] * sum_k F[s][tau-(768-L_s)][k][p]  (fused)
//   out[b][p][c] = sum_tau x[b][tau][c] Ktot[tau][p] + mlp_b
//
// Workspace layout (float offsets):
//   w    [s][d][i]        : 0        len 344064
//   Apow [s][2][65536]    : 344064   len 393216
//   Ktil (unused)         : 737280   len 258048
//   Ktot [tau][p]         : 995328   len 147456
//   Y    [z][p][i]        : 1142784  len 9437184   (dead after k_gemm_Q4;
//        S (chunk sums)   : 1142784  len 589824     reused by scan)
//        F (folded)       : 1732608  len 8257536
//   QT region (time-shared):
//     Wt [z][i][o]        : 10579968 len 12582912
//     Qb [s][d][12288]    : 10579968 len 16515072
// Total 27,095,040 floats (proven to fit)
// ---------------------------------------------------------------------------
#define W_OFF    0
#define AP_OFF   344064
#define KT_OFF   737280
#define KTOT_OFF 995328
#define Y_OFF    1142784
#define S_OFF    1142784
#define F_OFF    1732608
#define QT_OFF   10579968
#define WS_FLOATS 27095040

__device__ __forceinline__ int off_w_f(int s)  { return 49152  * ((1 << s) - 1); }
__device__ __forceinline__ int qoff_f(int s)   { return 2359296 * ((1 << s) - 1); }
__device__ __forceinline__ int foff_f(int s)   { return 1179648 * ((1 << s) - 1); }

// ---------------------------------------------------------------------------
// Chain tile: C[32x64 tile at (m0,n0)] = A[M x 256] @ op(B[256 x 256]),
// 256 threads, 2x4 microtile.  fmaf chain over k ascending in 16-chunks.
// ---------------------------------------------------------------------------
template<bool BT>
__device__ __forceinline__ void gemm_tile32(const float* __restrict__ A,
                                            const float* __restrict__ B,
                                            float* __restrict__ C,
                                            int M, int ldc, int m0, int n0)
{
    __shared__ float As[16][36];
    __shared__ float Bs[16][68];
    const int tid = threadIdx.x;
    const int tx = tid & 15;
    const int ty = tid >> 4;

    float acc[2][4] = {{0.f,0.f,0.f,0.f},{0.f,0.f,0.f,0.f}};

    for (int kk = 0; kk < 256; kk += 16) {
        if (tid < 128) {
            int r  = tid >> 2;
            int kq = (tid & 3) << 2;
            float4 av = make_float4(0.f, 0.f, 0.f, 0.f);
            if (m0 + r < M)
                av = *(const float4*)(A + (size_t)(m0 + r) * 256 + kk + kq);
            As[kq + 0][r] = av.x; As[kq + 1][r] = av.y;
            As[kq + 2][r] = av.z; As[kq + 3][r] = av.w;
        }
        if (BT) {
            int rb = tid >> 2;
            int kq = (tid & 3) << 2;
            float4 bv = *(const float4*)(B + (size_t)(n0 + rb) * 256 + kk + kq);
            Bs[kq + 0][rb] = bv.x; Bs[kq + 1][rb] = bv.y;
            Bs[kq + 2][rb] = bv.z; Bs[kq + 3][rb] = bv.w;
        } else {
            int kb = tid >> 4;
            int j4 = (tid & 15) << 2;
            float4 bv = *(const float4*)(B + (size_t)(kk + kb) * 256 + n0 + j4);
            *(float4*)(&Bs[kb][j4]) = bv;
        }
        __syncthreads();

        #pragma unroll
        for (int kq = 0; kq < 16; ++kq) {
            float a0 = As[kq][2 * ty];
            float a1 = As[kq][2 * ty + 1];
            float4 b4 = *(const float4*)(&Bs[kq][tx << 2]);
            acc[0][0] = fmaf(a0, b4.x, acc[0][0]);
            acc[0][1] = fmaf(a0, b4.y, acc[0][1]);
            acc[0][2] = fmaf(a0, b4.z, acc[0][2]);
            acc[0][3] = fmaf(a0, b4.w, acc[0][3]);
            acc[1][0] = fmaf(a1, b4.x, acc[1][0]);
            acc[1][1] = fmaf(a1, b4.y, acc[1][1]);
            acc[1][2] = fmaf(a1, b4.z, acc[1][2]);
            acc[1][3] = fmaf(a1, b4.w, acc[1][3]);
        }
        __syncthreads();
    }

    #pragma unroll
    for (int u = 0; u < 2; ++u) {
        int row = m0 + 2 * ty + u;
        if (row < M) {
            float4 cv = make_float4(acc[u][0], acc[u][1], acc[u][2], acc[u][3]);
            *(float4*)(C + (size_t)row * ldc + n0 + (tx << 2)) = cv;
        }
    }
}

// ---------------------------------------------------------------------------
// Workhorse (r7-proven): C[64][128] = A[64][256] @ B^T, K=256, 256 threads,
// 4x8 microtile, single-buffered.
// ---------------------------------------------------------------------------
__device__ __forceinline__ void gemm64x128_q(const float* __restrict__ A,
                                             const float* __restrict__ B,
                                             float* __restrict__ C, int ldc)
{
    __shared__ float As[16][68];
    __shared__ float Bs[16][132];

    const int tid = threadIdx.x;
    const int tx = tid & 15;
    const int ty = tid >> 4;
    const int ra  = tid >> 2;          // 0..63
    const int kqa = (tid & 3) << 2;    // 0,4,8,12
    const int rb  = tid >> 1;          // 0..127
    const int kq8 = (tid & 1) << 3;    // 0 or 8

    float acc[2][4][4];
    #pragma unroll
    for (int g = 0; g < 2; ++g)
        #pragma unroll
        for (int u = 0; u < 4; ++u)
            #pragma unroll
            for (int v = 0; v < 4; ++v) acc[g][u][v] = 0.f;

    for (int kk = 0; kk < 256; kk += 16) {
        float4 av = *(const float4*)(A + (size_t)ra * 256 + kk + kqa);
        As[kqa + 0][ra] = av.x; As[kqa + 1][ra] = av.y;
        As[kqa + 2][ra] = av.z; As[kqa + 3][ra] = av.w;

        const float* bp = B + (size_t)rb * 256 + kk + kq8;
        float4 b0 = *(const float4*)(bp);
        float4 b1 = *(const float4*)(bp + 4);
        Bs[kq8 + 0][rb] = b0.x; Bs[kq8 + 1][rb] = b0.y;
        Bs[kq8 + 2][rb] = b0.z; Bs[kq8 + 3][rb] = b0.w;
        Bs[kq8 + 4][rb] = b1.x; Bs[kq8 + 5][rb] = b1.y;
        Bs[kq8 + 6][rb] = b1.z; Bs[kq8 + 7][rb] = b1.w;
        __syncthreads();

        #pragma unroll
        for (int kq = 0; kq < 16; ++kq) {
            float4 a   = *(const float4*)(&As[kq][4 * ty]);
            float4 b0v = *(const float4*)(&Bs[kq][4 * tx]);
            float4 b1v = *(const float4*)(&Bs[kq][4 * tx + 64]);
            float af[4] = {a.x, a.y, a.z, a.w};
            float bf[8] = {b0v.x, b0v.y, b0v.z, b0v.w, b1v.x, b1v.y, b1v.z, b1v.w};
            #pragma unroll
            for (int g = 0; g < 2; ++g)
                #pragma unroll
                for (int u = 0; u < 4; ++u)
                    #pragma unroll
                    for (int v = 0; v < 4; ++v)
                        acc[g][u][v] = fmaf(af[u], bf[g * 4 + v], acc[g][u][v]);
        }
        __syncthreads();
    }

    #pragma unroll
    for (int u = 0; u < 4; ++u) {
        int row = 4 * ty + u;
        #pragma unroll
        for (int g = 0; g < 2; ++g) {
            float4 cv = make_float4(acc[g][u][0], acc[g][u][1],
                                    acc[g][u][2], acc[g][u][3]);
            *(float4*)(C + (size_t)row * ldc + 4 * tx + 64 * g) = cv;
        }
    }
}

// ---------------------------------------------------------------------------
// Transpose body: Wt[s][ri][k][i][o] = W[i][o][k]  (LDS-staged, coalesced)
// ---------------------------------------------------------------------------
__device__ __forceinline__ void transpose_body(int bid,
    const float* Wr0, const float* Wi0, const float* Wr1, const float* Wi1,
    const float* Wr2, const float* Wi2, float* ws)
{
    __shared__ float t[256][33];
    int i  = bid & 255;
    int ri = (bid >> 8) & 1;
    int s  = bid >> 9;
    const float* W;
    if (s == 0)      W = ri ? Wi0 : Wr0;
    else if (s == 1) W = ri ? Wi1 : Wr1;
    else             W = ri ? Wi2 : Wr2;

    const int tid = threadIdx.x;
    const float* slab = W + (size_t)i * 8192;
    #pragma unroll
    for (int j = 0; j < 8; ++j) {
        int f = j * 1024 + tid * 4;
        float4 v = *(const float4*)(slab + f);
        int o = f >> 5;
        int k = f & 31;
        t[o][k + 0] = v.x; t[o][k + 1] = v.y;
        t[o][k + 2] = v.z; t[o][k + 3] = v.w;
    }
    __syncthreads();

    int sri = s * 2 + ri;
    #pragma unroll
    for (int k = 0; k < 32; ++k) {
        ws[QT_OFF + (size_t)(sri * 32 + k) * 65536 + (size_t)i * 256 + tid] = t[tid][k];
    }
}

// ---------------------------------------------------------------------------
// Level-0 + transpose merged launch: grid (4, 16, 27).
//   z < 3  : chain level 0 for scale s = z (jump w[1] = A @ Bv; square; w[0]=Bv)
//   z >= 3 : transpose block bid = (z-3)*64 + y*4 + x   (24*64 = 1536 blocks)
// ---------------------------------------------------------------------------
__global__ void __launch_bounds__(256)
k_lvl0t(const float* A0, const float* A1, const float* A2,
        const float* B0, const float* B1, const float* B2,
        const float* Wr0, const float* Wi0, const float* Wr1, const float* Wi1,
        const float* Wr2, const float* Wi2, float* ws)
{
    const int z = blockIdx.z;
    if (z >= 3) {
        int bid = (z - 3) * 64 + blockIdx.y * 4 + blockIdx.x;
        transpose_body(bid, Wr0, Wi0, Wr1, Wi1, Wr2, Wi2, ws);
        return;
    }

    const int s = z;
    const float* Ain = (s == 0) ? A0 : (s == 1) ? A1 : A2;
    const float* Bv  = (s == 0) ? B0 : (s == 1) ? B1 : B2;
    float* wbase = ws + W_OFF + off_w_f(s);
    float* bufA  = ws + AP_OFF + s * 131072;

    const int y = blockIdx.y;
    const int n0col = blockIdx.x * 64;

    if (y == 15 && blockIdx.x == 3)
        ws[W_OFF + off_w_f(s) + threadIdx.x] = Bv[threadIdx.x];

    if (y < 8) {
        if (y == 0)   // cnt = 1 row
            gemm_tile32<true>(Bv, Ain, wbase + 256, 1, 256, 0, n0col);
    } else {
        gemm_tile32<false>(Ain, Ain, bufA, 256, 256, (y - 8) * 32, n0col);
    }
}

// ---------------------------------------------------------------------------
// doubling level n (32x64 tiles): jump + square.  n >= 1.
// grid (4, 16, nz), scale s = z + sbase.
// ---------------------------------------------------------------------------
__global__ void k_level2(int n, int sbase, const float* A0, const float* A1,
                         const float* A2, float* ws)
{
    int s = blockIdx.z + sbase;
    int L = 192 << s;
    float* wbase = ws + W_OFF + off_w_f(s);
    float* bufA  = ws + AP_OFF + s * 131072;
    float* bufB  = bufA + 65536;
    const float* src = ((n - 1) & 1) ? bufB : bufA;

    const int y = blockIdx.y;
    const int n0col = blockIdx.x * 64;

    if (y < 8) {
        int p2 = 1 << n;
        if (p2 >= L) return;
        int cnt = min(p2, L - p2);
        int m0 = y * 32;
        if (m0 >= cnt) return;
        gemm_tile32<true>(wbase, src, wbase + (size_t)p2 * 256, cnt, 256, m0, n0col);
    } else {
        if ((2 << n) >= L) return;
        float* dst = (n & 1) ? bufB : bufA;
        gemm_tile32<false>(src, src, dst, 256, 256, (y - 8) * 32, n0col);
    }
}

// ---------------------------------------------------------------------------
// Y[z][p][i] = sum_o E[L-192+p][o] * Wt[z][i][o]
// grid (2, 3, 192): x = i-half (128 cols), y = p-tile, z = (s,ri,k).
// ---------------------------------------------------------------------------
__global__ void __launch_bounds__(256, 4)
k_gemm_Y5(const float* E0, const float* E1, const float* E2, float* __restrict__ ws)
{
    const int z  = blockIdx.z;                   // (s,ri,k)
    const int s  = z >> 6;
    const int L  = 192 << s;
    const int n0 = blockIdx.x * 128;             // i half
    const int m0 = blockIdx.y * 64;              // p tile
    const float* E = (s == 0) ? E0 : (s == 1) ? E1 : E2;

    const float* Ap = E + (size_t)(L - 192) * 256 + (size_t)m0 * 256;
    const float* Bp = ws + QT_OFF + (size_t)z * 65536 + (size_t)n0 * 256;
    float* Cp = ws + Y_OFF + (size_t)z * 49152 + (size_t)m0 * 256 + n0;
    gemm64x128_q(Ap, Bp, Cp, 256);
}

// ---------------------------------------------------------------------------
// Qb[s][d][n] = sum_i w[s][d][i] * Y[n][i],  n = (ri*32+k)*192+p
// grid (96, 21): x = 128-col tile of n, y = packed (s, d-tile).  256 threads.
// ---------------------------------------------------------------------------
__global__ void __launch_bounds__(256, 4)
k_gemm_Q4(float* __restrict__ ws)
{
    const int y = blockIdx.y;
    int s, yt;
    if (y < 3)      { s = 0; yt = y; }
    else if (y < 9) { s = 1; yt = y - 3; }
    else            { s = 2; yt = y - 9; }
    const int m0 = yt * 64;
    const int n0 = blockIdx.x * 128;

    const float* Ap = ws + W_OFF + off_w_f(s) + (size_t)m0 * 256;
    const float* Bp = ws + Y_OFF + (size_t)s * 3145728 + (size_t)n0 * 256;
    float* Cp = ws + QT_OFF + qoff_f(s) + (size_t)m0 * 12288 + n0;
    gemm64x128_q(Ap, Bp, Cp, 12288);
}

// ---------------------------------------------------------------------------
// Pass 1 of chunked twiddled scan: complex chunk sums (16 chunks of L/16).
// grid (16, 32, 3), block 192 (= p)
// ---------------------------------------------------------------------------
__global__ void k_scanA(float* __restrict__ ws)
{
    const int c = blockIdx.x;
    const int k = blockIdx.y;
    const int s = blockIdx.z;
    const int L = 192 << s;
    const int C = L >> 4;
    const int p = threadIdx.x;

    __shared__ float twc[768], tws[768];
    for (int m = p; m < L; m += 192) {
        float ang = -2.f * PI_F * (float)m / (float)L;
        float ss, cc; sincosf(ang, &ss, &cc);
        twc[m] = cc; tws[m] = ss;
    }
    __syncthreads();

    const float* Qr = ws + QT_OFF + qoff_f(s) + (size_t)k * 192;
    const float* Qi = Qr + 6144;

    float ar = 0.f, ai = 0.f;
    const int d0 = c * C;
    int ph = (k * d0) % L;
    for (int j = 0; j < C; ++j) {
        int d = d0 + j;
        float qr = Qr[(size_t)d * 12288 + p];
        float qi = Qi[(size_t)d * 12288 + p];
        float cc = twc[ph], sn = tws[ph];
        ar = fmaf(cc, qr, fmaf(-sn, qi, ar));
        ai = fmaf(cc, qi, fmaf( sn, qr, ai));
        ph += k; if (ph >= L) ph -= L;
    }
    size_t sb = (size_t)((s * 32 + k) * 16 + c) * 384;
    ws[S_OFF + sb + p]       = ar;
    ws[S_OFF + sb + 192 + p] = ai;
}

// ---------------------------------------------------------------------------
// Pass 2: offset from chunk sums, rescan own chunk, fold phase into F.
// grid (16, 32, 3), block 192
// ---------------------------------------------------------------------------
__global__ void k_scanB(float* __restrict__ ws)
{
    const int c = blockIdx.x;
    const int k = blockIdx.y;
    const int s = blockIdx.z;
    const int L = 192 << s;
    const int C = L >> 4;
    const int p = threadIdx.x;

    __shared__ float twc[768], tws[768];
    for (int m = p; m < L; m += 192) {
        float ang = -2.f * PI_F * (float)m / (float)L;
        float ss, cc; sincosf(ang, &ss, &cc);
        twc[m] = cc; tws[m] = ss;
    }
    __syncthreads();

    float ar = 0.f, ai = 0.f;
    size_t sbase = (size_t)(s * 32 + k) * 16 * 384;
    for (int c2 = 0; c2 < c; ++c2) {
        ar += ws[S_OFF + sbase + (size_t)c2 * 384 + p];
        ai += ws[S_OFF + sbase + (size_t)c2 * 384 + 192 + p];
    }

    const float ck = ((k == 0) ? 1.f : 2.f) / (float)L;
    const float* Qr = ws + QT_OFF + qoff_f(s) + (size_t)k * 192;
    const float* Qi = Qr + 6144;
    float* F = ws + F_OFF + foff_f(s);

    const int d0 = c * C;
    int ph = (k * d0) % L;
    int m1 = d0 + 192 - L; if (m1 < 0) m1 += L;
    int ph2 = (k * m1) % L;
    for (int j = 0; j < C; ++j) {
        int d = d0 + j;
        float qr = Qr[(size_t)d * 12288 + p];
        float qi = Qi[(size_t)d * 12288 + p];
        float cc = twc[ph], sn = tws[ph];
        ar = fmaf(cc, qr, fmaf(-sn, qi, ar));
        ai = fmaf(cc, qi, fmaf( sn, qr, ai));
        float f = ck * fmaf(twc[ph2], ar, tws[ph2] * ai);
        int sidx = L - 1 - d;
        F[((size_t)sidx * 32 + k) * 192 + p] = f;
        ph  += k; if (ph  >= L) ph  -= L;
        ph2 += k; if (ph2 >= L) ph2 -= L;
    }
}

// ---------------------------------------------------------------------------
// Fused k-reduction + scale-combine:
//   Ktot[tau][p] = sum_s (tau >= 768-L_s) mlp_w[s] * sum_k F[s][tau-(768-L_s)][k][p]
// grid (768), block 192
// ---------------------------------------------------------------------------
__global__ void k_kredc(float* __restrict__ ws, const float* __restrict__ mw)
{
    const int tau = blockIdx.x;
    const int p   = threadIdx.x;
    float sum = 0.f;
    #pragma unroll
    for (int s = 0; s < 3; ++s) {
        int L = 192 << s;
        int off = 768 - L;
        if (tau >= off) {
            int sidx = tau - off;
            const float* F = ws + F_OFF + foff_f(s) + (size_t)sidx * 32 * 192;
            float kt = 0.f;
            #pragma unroll
            for (int k = 0; k < 32; ++k)
                kt += F[k * 192 + p];
            sum = fmaf(mw[s], kt, sum);
        }
    }
    ws[KTOT_OFF + (size_t)tau * 192 + p] = sum;
}

// ---------------------------------------------------------------------------
__global__ void k_out(const float* __restrict__ x, const float* __restrict__ ws,
                      const float* __restrict__ mb, float* __restrict__ out)
{
    int bid = blockIdx.x;
    int b = bid / 21;
    int c = bid - b * 21;
    __shared__ float xl[768];
    for (int t = threadIdx.x; t < 768; t += 192)
        xl[t] = x[((size_t)b * 768 + t) * 21 + c];
    __syncthreads();

    int p = threadIdx.x;
    const float* K = ws + KTOT_OFF;
    float acc = 0.f;
    for (int tau = 0; tau < 768; ++tau)
        acc = fmaf(xl[tau], K[(size_t)tau * 192 + p], acc);
    out[((size_t)b * 192 + p) * 21 + c] = acc + mb[0];
}

// ---------------------------------------------------------------------------
extern "C" void kernel_launch(void* const* d_in, const int* in_sizes, int n_in,
                              void* d_out, int out_size, void* d_ws, size_t ws_size,
                              hipStream_t stream)
{
    const float* x   = (const float*)d_in[0];
    const float* A0  = (const float*)d_in[1];
    const float* B0  = (const float*)d_in[2];
    const float* E0  = (const float*)d_in[3];
    const float* Wr0 = (const float*)d_in[4];
    const float* Wi0 = (const float*)d_in[5];
    const float* A1  = (const float*)d_in[6];
    const float* B1  = (const float*)d_in[7];
    const float* E1  = (const float*)d_in[8];
    const float* Wr1 = (const float*)d_in[9];
    const float* Wi1 = (const float*)d_in[10];
    const float* A2  = (const float*)d_in[11];
    const float* B2  = (const float*)d_in[12];
    const float* E2  = (const float*)d_in[13];
    const float* Wr2 = (const float*)d_in[14];
    const float* Wi2 = (const float*)d_in[15];
    const float* mw  = (const float*)d_in[16];
    const float* mb  = (const float*)d_in[17];
    float* ws  = (float*)d_ws;
    float* out = (float*)d_out;

    if (ws_size < (size_t)WS_FLOATS * sizeof(float)) {
        hipMemsetAsync(d_out, 0, (size_t)out_size * sizeof(float), stream);
        return;
    }

    // level 0 (all scales) + all 1536 transpose blocks in one launch
    k_lvl0t<<<dim3(4, 16, 27), 256, 0, stream>>>(
        A0, A1, A2, B0, B1, B2, Wr0, Wi0, Wr1, Wi1, Wr2, Wi2, ws);
    for (int n = 1; n < 8; ++n)
        k_level2<<<dim3(4, 16, 3), 256, 0, stream>>>(n, 0, A0, A1, A2, ws);
    k_level2<<<dim3(4, 16, 2), 256, 0, stream>>>(8, 1, A0, A1, A2, ws);  // s=1,2
    k_level2<<<dim3(4, 16, 1), 256, 0, stream>>>(9, 2, A0, A1, A2, ws);  // s=2
    k_gemm_Y5<<<dim3(2, 3, 192), 256, 0, stream>>>(E0, E1, E2, ws);
    k_gemm_Q4<<<dim3(96, 21), 256, 0, stream>>>(ws);
    k_scanA<<<dim3(16, 32, 3), 192, 0, stream>>>(ws);
    k_scanB<<<dim3(16, 32, 3), 192, 0, stream>>>(ws);
    k_kredc<<<768, 192, 0, stream>>>(ws, mw);
    k_out<<<336, 192, 0, stream>>>(x, ws, mb, out);
}